// Round 5
// baseline (486.331 us; speedup 1.0000x reference)
//
#include <hip/hip_runtime.h>
#include <hip/hip_bf16.h>

// DA-RNN persistent kernel, round 5.
// R5 vs R4: (1) __launch_bounds__(512,2) — R4's VGPR_Count=128 cap caused ~25MB
// of scratch spill traffic; (2) the two 512-col gates GEMMs go i8
// (mfma_i32_16x16x64_i8, K=64): per-column weight scales, per-row dynamic
// x_tilde scale (folded into softmax reduction), fixed 1/127 for h/d — halves
// the dominant L2 weight stream (262->131 KB/CU/step); (3) B-fragments
// register-prefetched a phase early to hide L2 latency across barriers.

#define B_    1024
#define T_    64
#define D_    128
#define H_    128
#define HOR_  24
#define ATT_  64
#define BB    4
#define LOG2E 1.4426950408889634f
#define C127  (1.f/127.f)

typedef float f32x4  __attribute__((ext_vector_type(4)));
typedef short bf16x8 __attribute__((ext_vector_type(8)));
typedef int   i32x4  __attribute__((ext_vector_type(4)));

#define MFMA16(a,b,c) __builtin_amdgcn_mfma_f32_16x16x32_bf16((a),(b),(c),0,0,0)
#define MFMAI8(a,b,c) __builtin_amdgcn_mfma_i32_16x16x64_i8((a),(b),(c),0,0,0)

// ---- workspace layout ----
// bf16 frag elements (shorts), base = ws
#define WHS_E    0        // base GEMM  B: kt0..7, nt0..3  (16384 el)
#define WDDC_E   16384    // dc GEMM    B: kt0..7, nt0..3  (16384 el)
#define WDENC_E  32768    // proj GEMM  B: kt0..3, nt0..3  ( 8192 el)
// byte offsets
#define WENC8_B  81920    // i8 enc gates B: [kt4][nt32][lane64][16]  (131072 B)
#define WDEC8_B  212992   // i8 dec gates B: [kt2][nt32][lane64][16]  ( 65536 B)
#define SENC_B   278528   // 512 f32 per-col scales (enc)
#define SDEC_B   280576   // 512 f32 per-col scales (dec)
#define ENCH_B   282624   // enc_hiddens bf16 [B][T][H] (16 MiB)

__device__ __forceinline__ short f2b(float f) {        // fp32 -> bf16 RNE
  union { float f; unsigned u; } c; c.f = f;
  unsigned r = c.u + 0x7fffu + ((c.u >> 16) & 1u);
  return (short)(r >> 16);
}
__device__ __forceinline__ float b2f(short s) {
  union { unsigned u; float f; } c; c.u = ((unsigned)(unsigned short)s) << 16;
  return c.f;
}
__device__ __forceinline__ float fexp2(float x) { return __builtin_amdgcn_exp2f(x); }
__device__ __forceinline__ float frcp (float x) { return __builtin_amdgcn_rcpf(x); }
__device__ __forceinline__ float tanh_acc(float x) {   // 1 - 2/(1+e^{2x})
  float e = fexp2(x * 2.885390081777927f);
  return 1.f - 2.f * frcp(1.f + e);
}
__device__ __forceinline__ float sigm(float x) {
  return frcp(1.f + fexp2(-LOG2E * x));
}
__device__ __forceinline__ float wsum64(float v) {
#pragma unroll
  for (int o = 32; o > 0; o >>= 1) v += __shfl_xor(v, o, 64);
  return v;
}
__device__ __forceinline__ float wmax64(float v) {
#pragma unroll
  for (int o = 32; o > 0; o >>= 1) v = fmaxf(v, __shfl_xor(v, o, 64));
  return v;
}

// ---- pack weights: bf16 B-frags (small GEMMs) + i8 B-frags w/ col scales ----
// bf16 B-frag (16x16x32): lane L holds B[k=kt*32+(L>>4)*8+j][n=nt*16+(L&15)]
// i8   B-frag (16x16x64): lane L holds B[k=kt*64+(L>>4)*16+b][n=nt*16+(L&15)]
__global__ void prep(const float* __restrict__ We_w,
                     const float* __restrict__ enc_Wih,
                     const float* __restrict__ enc_Whh,
                     const float* __restrict__ dec_Whh,
                     const float* __restrict__ Wd_w,
                     char* __restrict__ ws8) {
  int g = blockIdx.x * 256 + threadIdx.x;
  short* f16 = (short*)ws8;
  if (g < 40960) {
    int region = g >> 14;              // 0=WHS 1=WDDC 2=WDENC
    int er = g & 16383;
    int fi = er >> 9, li = (er >> 3) & 63, jq = er & 7;
    int kt = fi >> 2, nt = fi & 3;
    int k = kt * 32 + ((li >> 4) << 3) + jq, n = nt * 16 + (li & 15);
    float v;
    if (region == 0)      v = We_w[n * 257 + k];                       // [h,c]->base
    else if (region == 1) v = (k < 128) ? Wd_w[n * 384 + 128 + k]
                                        : Wd_w[n * 384 + 256 + (k - 128)]; // dc
    else                  v = Wd_w[n * 384 + k];                       // proj
    f16[g] = f2b(v);
  } else if (g < 40960 + 512) {        // encoder gates column n (K=256)
    int n = g - 40960;
    const float* c0 = enc_Wih + n * 128;
    const float* c1 = enc_Whh + n * 128;
    float m = 0.f;
    for (int k = 0; k < 128; ++k) { m = fmaxf(m, fabsf(c0[k])); m = fmaxf(m, fabsf(c1[k])); }
    ((float*)(ws8 + SENC_B))[n] = m * C127;
    float inv = m > 0.f ? 127.f / m : 0.f;
    char* dst = ws8 + WENC8_B;
    int nt = n >> 4, nc = n & 15;
    for (int k = 0; k < 256; ++k) {
      float wv = (k < 128) ? c0[k] : c1[k - 128];
      int q = (int)rintf(wv * inv);
      int kt = k >> 6, grp = (k >> 4) & 3, b = k & 15, lane = nc | (grp << 4);
      dst[((kt * 32 + nt) * 64 + lane) * 16 + b] = (char)q;
    }
  } else if (g < 40960 + 1024) {       // decoder gates column n (K=128)
    int n = g - 40960 - 512;
    const float* c0 = dec_Whh + n * 128;
    float m = 0.f;
    for (int k = 0; k < 128; ++k) m = fmaxf(m, fabsf(c0[k]));
    ((float*)(ws8 + SDEC_B))[n] = m * C127;
    float inv = m > 0.f ? 127.f / m : 0.f;
    char* dst = ws8 + WDEC8_B;
    int nt = n >> 4, nc = n & 15;
    for (int k = 0; k < 128; ++k) {
      int q = (int)rintf(c0[k] * inv);
      int kt = k >> 6, grp = (k >> 4) & 3, b = k & 15, lane = nc | (grp << 4);
      dst[((kt * 32 + nt) * 64 + lane) * 16 + b] = (char)q;
    }
  }
}

__global__ __launch_bounds__(512, 2)
void da_rnn(const float* __restrict__ X, const float* __restrict__ y_hist,
            const float* __restrict__ We_w, const float* __restrict__ We_b,
            const float* __restrict__ ve_w,
            const float* __restrict__ enc_bih, const float* __restrict__ enc_bhh,
            const float* __restrict__ dec_Wih,
            const float* __restrict__ dec_bih, const float* __restrict__ dec_bhh,
            const float* __restrict__ Wd_b, const float* __restrict__ vd_w,
            const float* __restrict__ fc_w, const float* __restrict__ fc_b,
            const char* __restrict__ ws8, float* __restrict__ out) {
  const short* f16  = (const short*)ws8;
  const i32x4* enc8 = (const i32x4*)(ws8 + WENC8_B);
  const i32x4* dec8 = (const i32x4*)(ws8 + WDEC8_B);
  const float* senc = (const float*)(ws8 + SENC_B);
  const float* sdec = (const float*)(ws8 + SDEC_B);
  short* ench = (short*)(ws8 + ENCH_B);

  // i8 A staging: rows padded to 272 B (68 words) -> quarter-wave rows give
  // 2-way bank aliasing (free). bf16 s_Ahc rows 264 shorts as in R3.
  __shared__ __align__(16) char  s_A8[16][272];   // gates A: [x_tilde_q ; h_q] / dec: [d_q]
  __shared__ __align__(16) short s_Ahc[16][264];  // base/dc/proj A: [h ; c] bf16
  __shared__ short s_projT[4][64][65];            // enc_proj^T, LDS-resident
  __shared__ float s_gates[4][512];               // dec P4/P5: [0,128) h-mirror, [128,256) ctx
  __shared__ float s_base[4][64];                 // enc: base ; dec: dc
  __shared__ float s_beta[4][64];
  __shared__ float s_ps[4][2][64];
  __shared__ float s_red[4][4];                   // [r][0..1]=sum halves, [2..3]=max halves
  __shared__ float s_xr[4];                       // per-row x_tilde dequant scale
  __shared__ float2 s_wv[64];                     // (w_feat[k], ve_w[k])
  __shared__ float s_web[64], s_vd[64], s_wdb[64];
  __shared__ float s_se[512], s_sd[512];          // per-col weight scales
  __shared__ float s_yprev[4], s_yhdot[4];
  // Chebyshev attention state
  __shared__ __align__(16) float s_fn[4][8][16];
  __shared__ float s_cc[4][8];
  __shared__ float s_dctm[8][8];
  __shared__ float s_xn[8];

  const int tid  = threadIdx.x;
  const int lane = tid & 63;
  const int w    = tid >> 6;        // wave 0..7
  const int half = w & 1;
  const int b0   = blockIdx.x * BB;
  const int rr   = tid >> 7;        // row 0..3
  const int jj   = tid & 127;       // feature

  if (tid < 64) {
    s_wv[tid]  = make_float2(We_w[tid * 257 + 256], ve_w[tid]);
    s_web[tid] = We_b[tid];
    s_vd[tid]  = vd_w[tid];
    s_wdb[tid] = Wd_b[tid];
    int dj = tid >> 3, di = tid & 7;
    s_dctm[dj][di] = ((dj == 0 ? 1.f : 2.f) / 8.f) *
                     cosf((float)dj * (2 * di + 1) * 0.19634954084936207f); // pi/16
  }
  if (tid < 8) s_xn[tid] = 6.f * cosf((2 * tid + 1) * 0.19634954084936207f);
  s_se[tid] = senc[tid];
  s_sd[tid] = sdec[tid];
  if (tid < 256) s_base[tid >> 6][tid & 63] = We_b[tid & 63];  // base_0 (h0=c0=0)
  for (int i = tid; i < (16 * 272) / 4; i += 512) ((int*)s_A8)[i] = 0;
  for (int i = tid; i < 12 * 256; i += 512) {      // zero bf16 pad rows 4..15
    int r = 4 + (i >> 8), ci = i & 255;
    s_Ahc[r][ci] = 0;
  }
  // per-thread register constants
  const float encb0 = enc_bih[jj]       + enc_bhh[jj];
  const float encb1 = enc_bih[jj + 128] + enc_bhh[jj + 128];
  const float encb2 = enc_bih[jj + 256] + enc_bhh[jj + 256];
  const float encb3 = enc_bih[jj + 384] + enc_bhh[jj + 384];
  const float decb0 = dec_bih[jj]       + dec_bhh[jj];
  const float decb1 = dec_bih[jj + 128] + dec_bhh[jj + 128];
  const float decb2 = dec_bih[jj + 256] + dec_bhh[jj + 256];
  const float decb3 = dec_bih[jj + 384] + dec_bhh[jj + 384];
  const float dwih0 = dec_Wih[jj],       dwih1 = dec_Wih[jj + 128];
  const float dwih2 = dec_Wih[jj + 256], dwih3 = dec_Wih[jj + 384];
  const float fcw0 = fc_w[lane],       fcw1 = fc_w[64 + lane];
  const float fcw2 = fc_w[128 + lane], fcw3 = fc_w[192 + lane];
  const float fb0 = fc_b[0];

  float h = 0.f, c = 0.f;
  float x = X[((b0 + rr) * T_ + 0) * D_ + jj];
  __syncthreads();

  // ====================== encoder ======================
  for (int t = 0; t < T_; ++t) {
    // prefetch gates B-frags (pure L2 reads, no deps) — in flight through Ba/Bb/attn
    i32x4 pfe[4][4];
#pragma unroll
    for (int kt = 0; kt < 4; ++kt)
#pragma unroll
      for (int i = 0; i < 4; ++i)
        pfe[kt][i] = enc8[(kt * 32 + (w + 8 * i)) * 64 + lane];

    // ---- Ba: evaluate f_r at 8 Chebyshev nodes (thread = (r, node, kchunk)) ----
    {
      const int r = tid >> 7, ni = (tid >> 4) & 7, kc = tid & 15;
      const float xi = s_xn[ni];
      const float4 wv01 = *(const float4*)&s_wv[kc * 4];
      const float4 wv23 = *(const float4*)&s_wv[kc * 4 + 2];
      const float4 bb   = *(const float4*)&s_base[r][kc * 4];
      float p;
      p  = wv01.y * tanh_acc(fmaf(xi, wv01.x, bb.x));
      p += wv01.w * tanh_acc(fmaf(xi, wv01.z, bb.y));
      p += wv23.y * tanh_acc(fmaf(xi, wv23.x, bb.z));
      p += wv23.w * tanh_acc(fmaf(xi, wv23.z, bb.w));
      s_fn[r][ni][kc] = p;
    }
    __syncthreads();                                                // SYNC Ba
    // ---- Bb: reduce + DCT -> Chebyshev coeffs (64 threads) ----
    if (tid < 64) {
      const int r = tid >> 4, j = (tid >> 1) & 7, ih = tid & 1;
      float acc = 0.f;
#pragma unroll
      for (int ii = 0; ii < 4; ++ii) {
        int i = ih * 4 + ii;
        const float4 f0 = *(const float4*)&s_fn[r][i][0];
        const float4 f1 = *(const float4*)&s_fn[r][i][4];
        const float4 f2 = *(const float4*)&s_fn[r][i][8];
        const float4 f3 = *(const float4*)&s_fn[r][i][12];
        float fi = ((f0.x + f0.y) + (f0.z + f0.w)) + ((f1.x + f1.y) + (f1.z + f1.w))
                 + ((f2.x + f2.y) + (f2.z + f2.w)) + ((f3.x + f3.y) + (f3.z + f3.w));
        acc = fmaf(s_dctm[j][i], fi, acc);
      }
      acc += __shfl_xor(acc, 1, 64);
      if (ih == 0) s_cc[r][j] = acc;
    }
    __syncthreads();                                                // SYNC Bb
    // ---- eval: Clenshaw + softmax + i8 quantize (thread = (rr, jj)) ----
    {
      float u  = fminf(fmaxf(x * (1.f / 6.f), -1.f), 1.f);
      float u2 = u + u;
      float bk1 = s_cc[rr][7];
      float bk  = fmaf(u2, bk1, s_cc[rr][6]);
      float bn;
      bn = fmaf(u2, bk, s_cc[rr][5] - bk1); bk1 = bk; bk = bn;
      bn = fmaf(u2, bk, s_cc[rr][4] - bk1); bk1 = bk; bk = bn;
      bn = fmaf(u2, bk, s_cc[rr][3] - bk1); bk1 = bk; bk = bn;
      bn = fmaf(u2, bk, s_cc[rr][2] - bk1); bk1 = bk; bk = bn;
      bn = fmaf(u2, bk, s_cc[rr][1] - bk1); bk1 = bk; bk = bn;
      float sc = fmaf(u, bk, s_cc[rr][0] - bk1);
      float e = fexp2(sc * LOG2E);        // no max-pass: |sc| <= sum|ve| ~ 2.6
      float ps = wsum64(e);
      float pm = wmax64(e * fabsf(x));    // max|x_tilde| = max(e|x|)/sum
      if (lane == 0) { s_red[rr][half] = ps; s_red[rr][2 + half] = pm; }
      __syncthreads();                                              // SYNC 1
      float sum = s_red[rr][0] + s_red[rr][1];
      float rmx = fmaxf(s_red[rr][2], s_red[rr][3]);
      float inv = rmx > 0.f ? 127.f * frcp(rmx) : 0.f;
      float qv = fminf(fmaxf(x * e * inv, -127.f), 127.f);
      s_A8[rr][jj] = (char)(int)rintf(qv);
      if (jj == 0) s_xr[rr] = rmx * frcp(127.f * sum);  // A dequant scale
    }
    float xn = 0.f;
    if (t < T_ - 1) xn = X[((b0 + rr) * T_ + t + 1) * D_ + jj];     // prefetch
    __syncthreads();                                                // SYNC 2
    // ---- gates i8 GEMM: [xt_q ; h_q] @ Wq^T  (8 waves, K=256 = 4 x K64) ----
    bf16x8 pfb[8];
    {
      i32x4 a0 = *(const i32x4*)&s_A8[lane & 15][  0 + ((lane >> 4) << 4)];
      i32x4 a1 = *(const i32x4*)&s_A8[lane & 15][ 64 + ((lane >> 4) << 4)];
      i32x4 a2 = *(const i32x4*)&s_A8[lane & 15][128 + ((lane >> 4) << 4)];
      i32x4 a3 = *(const i32x4*)&s_A8[lane & 15][192 + ((lane >> 4) << 4)];
      i32x4 ax[4], ah[4];
#pragma unroll
      for (int i = 0; i < 4; ++i) {
        i32x4 z = {0, 0, 0, 0};
        ax[i] = MFMAI8(a1, pfe[1][i], MFMAI8(a0, pfe[0][i], z));
        ah[i] = MFMAI8(a3, pfe[3][i], MFMAI8(a2, pfe[2][i], z));
      }
      // prefetch bf16 frags for the fused base|proj phase (flight over GEMM+epi)
      if (w < 4) {
#pragma unroll
        for (int kt = 0; kt < 8; ++kt)
          pfb[kt] = *(const bf16x8*)(f16 + WHS_E + ((kt * 4 + w) * 64 + lane) * 8);
      } else {
#pragma unroll
        for (int kt = 0; kt < 4; ++kt)
          pfb[kt] = *(const bf16x8*)(f16 + WDENC_E + ((kt * 4 + (w - 4)) * 64 + lane) * 8);
      }
      if (lane < 16) {
        float sx0 = s_xr[0], sx1 = s_xr[1], sx2 = s_xr[2], sx3 = s_xr[3];
#pragma unroll
        for (int i = 0; i < 4; ++i) {
          int col = (w + 8 * i) * 16 + lane;
          float se = s_se[col];
          s_gates[0][col] = se * fmaf(sx0, (float)ax[i][0], C127 * (float)ah[i][0]);
          s_gates[1][col] = se * fmaf(sx1, (float)ax[i][1], C127 * (float)ah[i][1]);
          s_gates[2][col] = se * fmaf(sx2, (float)ax[i][2], C127 * (float)ah[i][2]);
          s_gates[3][col] = se * fmaf(sx3, (float)ax[i][3], C127 * (float)ah[i][3]);
        }
      }
    }
    __syncthreads();                                                // SYNC 3
    // ---- LSTM epilogue ----
    {
      float gi = s_gates[rr][jj]       + encb0;
      float gf = s_gates[rr][jj + 128] + encb1;
      float gg = s_gates[rr][jj + 256] + encb2;
      float go = s_gates[rr][jj + 384] + encb3;
      c = sigm(gf) * c + sigm(gi) * tanh_acc(gg);
      h = sigm(go) * tanh_acc(c);
      short hb = f2b(h);
      s_A8[rr][128 + jj] = (char)(int)rintf(h * 127.f);  // h_q for t+1 gates
      s_Ahc[rr][jj]       = hb;                          // base/proj A
      s_Ahc[rr][128 + jj] = f2b(c);
      ench[((b0 + rr) * T_ + t) * H_ + jj] = hb;
      x = xn;
    }
    __syncthreads();                                                // SYNC 4
    // ---- fused: base_{t+1} (waves 0-3) | proj_t (waves 4-7), B from pfb ----
    if (w < 4) {
      f32x4 acc = {0.f, 0.f, 0.f, 0.f};
#pragma unroll
      for (int kt = 0; kt < 8; ++kt) {
        bf16x8 a = *(const bf16x8*)&s_Ahc[lane & 15][kt * 32 + ((lane >> 4) << 3)];
        acc = MFMA16(a, pfb[kt], acc);
      }
      if (lane < 16) {
        int col = w * 16 + lane; float bias = s_web[col];
#pragma unroll
        for (int r = 0; r < 4; ++r) s_base[r][col] = acc[r] + bias;
      }
    } else {
      f32x4 acc = {0.f, 0.f, 0.f, 0.f};
#pragma unroll
      for (int kt = 0; kt < 4; ++kt) {
        bf16x8 a = *(const bf16x8*)&s_Ahc[lane & 15][kt * 32 + ((lane >> 4) << 3)];
        acc = MFMA16(a, pfb[kt], acc);
      }
      if (lane < 16) {
        int katt = (w - 4) * 16 + lane;
#pragma unroll
        for (int r = 0; r < 4; ++r) s_projT[r][katt][t] = f2b(acc[r]);
      }
    }
    __syncthreads();                                                // SYNC 5
  }

  // ====================== decoder ======================
  h = 0.f; c = 0.f;                       // d, cc
  s_A8[rr][jj] = 0;                       // d_q = 0
  s_Ahc[rr][jj] = 0; s_Ahc[rr][128 + jj] = 0;
  if (tid < 4) s_yprev[tid] = y_hist[(b0 + tid) * T_ + (T_ - 1)];
  if (w < 4) {                            // fc_w[256:320] . y_hist (const per row)
    float p = fc_w[256 + lane] * y_hist[(b0 + w) * T_ + lane];
    p = wsum64(p);
    if (lane == 0) s_yhdot[w] = p;
  }
  __syncthreads();

  for (int hs = 0; hs < HOR_; ++hs) {
    // prefetch decoder B-frags
    i32x4 pfd[2][4];
#pragma unroll
    for (int kt = 0; kt < 2; ++kt)
#pragma unroll
      for (int i = 0; i < 4; ++i)
        pfd[kt][i] = dec8[(kt * 32 + (w + 8 * i)) * 64 + lane];
    bf16x8 pfc[8];
    if (w < 4) {
#pragma unroll
      for (int kt = 0; kt < 8; ++kt)
        pfc[kt] = *(const bf16x8*)(f16 + WDDC_E + ((kt * 4 + w) * 64 + lane) * 8);
    }
    // ---- P1: dec gates i8 (8 waves, K=128) + dc bf16 (waves 0-3, K=256) ----
    {
      i32x4 a0 = *(const i32x4*)&s_A8[lane & 15][ 0 + ((lane >> 4) << 4)];
      i32x4 a1 = *(const i32x4*)&s_A8[lane & 15][64 + ((lane >> 4) << 4)];
#pragma unroll
      for (int i = 0; i < 4; ++i) {
        i32x4 z = {0, 0, 0, 0};
        i32x4 ac = MFMAI8(a1, pfd[1][i], MFMAI8(a0, pfd[0][i], z));
        if (lane < 16) {
          int col = (w + 8 * i) * 16 + lane;
          float sd = s_sd[col] * C127;
#pragma unroll
          for (int r = 0; r < 4; ++r) s_gates[r][col] = sd * (float)ac[r];
        }
      }
    }
    if (w < 4) {
      f32x4 acc = {0.f, 0.f, 0.f, 0.f};
#pragma unroll
      for (int kt = 0; kt < 8; ++kt) {
        bf16x8 a = *(const bf16x8*)&s_Ahc[lane & 15][kt * 32 + ((lane >> 4) << 3)];
        acc = MFMA16(a, pfc[kt], acc);
      }
      if (lane < 16) {
        int col = w * 16 + lane; float bias = s_wdb[col];
#pragma unroll
        for (int r = 0; r < 4; ++r) s_base[r][col] = acc[r] + bias;
      }
    }
    __syncthreads();                                                // SYNC a
    // ---- P2: temporal attention partials (8 waves; lane = t') ----
    {
      const int r = w >> 1, kh = half;
      float acc = 0.f;
#pragma unroll 8
      for (int i = 0; i < 32; ++i) {
        int katt = kh * 32 + i;
        acc += s_vd[katt] * tanh_acc(b2f(s_projT[r][katt][lane]) + s_base[r][katt]);
      }
      s_ps[r][kh][lane] = acc;
    }
    __syncthreads();                                                // SYNC b
    // ---- P3: softmax over t' (waves 0-3; no max-pass) ----
    if (w < 4) {
      float sc2 = s_ps[w][0][lane] + s_ps[w][1][lane];
      float e = fexp2(sc2 * LOG2E);
      float ssum = wsum64(e);
      s_beta[w][lane] = e * frcp(ssum);
    }
    __syncthreads();                                                // SYNC c
    // ---- P4: context + LSTM epilogue (all threads) ----
    {
      float cx = 0.f;
      const short* ep = ench + (b0 + rr) * T_ * H_ + jj;
#pragma unroll 8
      for (int tp = 0; tp < 64; ++tp) cx = fmaf(s_beta[rr][tp], b2f(ep[tp * H_]), cx);
      float yp = s_yprev[rr];
      float gi = s_gates[rr][jj]       + decb0 + yp * dwih0;
      float gf = s_gates[rr][jj + 128] + decb1 + yp * dwih1;
      float gg = s_gates[rr][jj + 256] + decb2 + yp * dwih2;
      float go = s_gates[rr][jj + 384] + decb3 + yp * dwih3;
      c = sigm(gf) * c + sigm(gi) * tanh_acc(gg);
      h = sigm(go) * tanh_acc(c);
      s_gates[rr][jj]       = h;    // h-mirror for fc
      s_gates[rr][128 + jj] = cx;   // ctx for fc
      s_A8[rr][jj] = (char)(int)rintf(h * 127.f);   // d_q for next step
      s_Ahc[rr][jj]       = f2b(h);
      s_Ahc[rr][128 + jj] = f2b(c);
    }
    __syncthreads();                                                // SYNC d
    // ---- P5: fc = [d2, ctx, y_hist] . fc_w + fc_b (waves 0-3) ----
    if (w < 4) {
      float p = fcw0 * s_gates[w][lane]
              + fcw1 * s_gates[w][64 + lane]
              + fcw2 * s_gates[w][128 + lane]
              + fcw3 * s_gates[w][192 + lane];
      p = wsum64(p);
      if (lane == 0) {
        float o = p + fb0 + s_yhdot[w];
        out[(b0 + w) * HOR_ + hs] = o;
        s_yprev[w] = o;
      }
    }
    __syncthreads();                                                // SYNC e
  }
}

extern "C" void kernel_launch(void* const* d_in, const int* in_sizes, int n_in,
                              void* d_out, int out_size, void* d_ws, size_t ws_size,
                              hipStream_t stream) {
  (void)in_sizes; (void)n_in; (void)out_size; (void)ws_size;
  const float* X       = (const float*)d_in[0];
  const float* y_hist  = (const float*)d_in[1];
  const float* We_w    = (const float*)d_in[2];
  const float* We_b    = (const float*)d_in[3];
  const float* ve_w    = (const float*)d_in[4];
  // d_in[5] = ve_b : softmax-invariant, unused
  const float* enc_Wih = (const float*)d_in[6];
  const float* enc_Whh = (const float*)d_in[7];
  const float* enc_bih = (const float*)d_in[8];
  const float* enc_bhh = (const float*)d_in[9];
  const float* dec_Wih = (const float*)d_in[10];
  const float* dec_Whh = (const float*)d_in[11];
  const float* dec_bih = (const float*)d_in[12];
  const float* dec_bhh = (const float*)d_in[13];
  const float* Wd_w    = (const float*)d_in[14];
  const float* Wd_b    = (const float*)d_in[15];
  const float* vd_w    = (const float*)d_in[16];
  // d_in[17] = vd_b : softmax-invariant, unused
  const float* fc_w    = (const float*)d_in[18];
  const float* fc_b    = (const float*)d_in[19];

  char* ws8  = (char*)d_ws;
  float* out = (float*)d_out;

  prep<<<164, 256, 0, stream>>>(We_w, enc_Wih, enc_Whh, dec_Whh, Wd_w, ws8);
  da_rnn<<<B_ / BB, 512, 0, stream>>>(X, y_hist, We_w, We_b, ve_w,
                                      enc_bih, enc_bhh, dec_Wih, dec_bih, dec_bhh,
                                      Wd_b, vd_w, fc_w, fc_b, ws8, out);
}

// Round 6
// 351.253 us; speedup vs baseline: 1.3846x; 1.3846x over previous
//
#include <hip/hip_runtime.h>
#include <hip/hip_bf16.h>

// DA-RNN persistent kernel, round 6: chain-shortening restructure.
// 256 blocks x 512 threads, BB=4 rows/block, 1 block/CU.
// Key: R5 showed 63% stall cycles (chain-bound, not BW-bound). R6:
//  - ALL weights register-resident per wave (enc gates i8 16xi32x4, base/proj/
//    dc bf16 frags, dec gates i8) -> zero in-loop weight loads, no vmcnt drains
//  - waves 0-3 own one batch row each: attention / softmax / LSTM epilogue /
//    fc done IN-WAVE (shuffles, no LDS round-trips, no extra barriers)
//  - barycentric Chebyshev eval (8 nodes) replaces node->DCT->Clenshaw
//  - 4 barriers/enc step (was 7), 2/dec step (was 5)
//  - ench + projT fully LDS-resident (ench stored [j][t] for vector context
//    reads) -> global traffic in loop = X reads + out writes only

#define B_    1024
#define T_    64
#define D_    128
#define H_    128
#define HOR_  24
#define ATT_  64
#define BB    4
#define LOG2E 1.4426950408889634f
#define C127  (1.f/127.f)

typedef float f32x4  __attribute__((ext_vector_type(4)));
typedef short bf16x8 __attribute__((ext_vector_type(8)));
typedef int   i32x4  __attribute__((ext_vector_type(4)));

#define MFMA16(a,b,c) __builtin_amdgcn_mfma_f32_16x16x32_bf16((a),(b),(c),0,0,0)
#define MFMAI8(a,b,c) __builtin_amdgcn_mfma_i32_16x16x64_i8((a),(b),(c),0,0,0)

// ---- workspace layout (same packing as R5) ----
#define WHS_E    0        // base GEMM  B bf16: kt0..7, nt0..3  (16384 el)
#define WDDC_E   16384    // dc GEMM    B bf16: kt0..7, nt0..3  (16384 el)
#define WDENC_E  32768    // proj GEMM  B bf16: kt0..3, nt0..3  ( 8192 el)
#define WENC8_B  81920    // i8 enc gates B: [kt4][nt32][lane64][16] (131072 B)
#define WDEC8_B  212992   // i8 dec gates B: [kt2][nt32][lane64][16] ( 65536 B)
#define SENC_B   278528   // 512 f32 per-col scales (enc)
#define SDEC_B   280576   // 512 f32 per-col scales (dec)

__device__ __forceinline__ short f2b(float f) {        // fp32 -> bf16 RNE
  union { float f; unsigned u; } c; c.f = f;
  unsigned r = c.u + 0x7fffu + ((c.u >> 16) & 1u);
  return (short)(r >> 16);
}
__device__ __forceinline__ float b2f(short s) {
  union { unsigned u; float f; } c; c.u = ((unsigned)(unsigned short)s) << 16;
  return c.f;
}
__device__ __forceinline__ float fexp2(float x) { return __builtin_amdgcn_exp2f(x); }
__device__ __forceinline__ float frcp (float x) { return __builtin_amdgcn_rcpf(x); }
__device__ __forceinline__ float tanh_acc(float x) {   // 1 - 2/(1+e^{2x})
  float e = fexp2(x * 2.885390081777927f);
  return 1.f - 2.f * frcp(1.f + e);
}
__device__ __forceinline__ float sigm(float x) {
  return frcp(1.f + fexp2(-LOG2E * x));
}
__device__ __forceinline__ float wsum64(float v) {
#pragma unroll
  for (int o = 32; o > 0; o >>= 1) v += __shfl_xor(v, o, 64);
  return v;
}
__device__ __forceinline__ float wmax64(float v) {
#pragma unroll
  for (int o = 32; o > 0; o >>= 1) v = fmaxf(v, __shfl_xor(v, o, 64));
  return v;
}

// ---- prep1: bf16 B-frags (base / dc / proj), one element per thread ----
__global__ void prep_bf(const float* __restrict__ We_w,
                        const float* __restrict__ Wd_w,
                        char* __restrict__ ws8) {
  int e = blockIdx.x * 256 + threadIdx.x;
  if (e >= 40960) return;
  short* f16 = (short*)ws8;
  int region = e >> 14;                  // 0=WHS 1=WDDC 2=WDENC
  int er = e & 16383;
  int fi = er >> 9, li = (er >> 3) & 63, jq = er & 7;
  int kt = fi >> 2, nt = fi & 3;
  int k = kt * 32 + ((li >> 4) << 3) + jq, n = nt * 16 + (li & 15);
  float v;
  if (region == 0)      v = We_w[n * 257 + k];
  else if (region == 1) v = (k < 128) ? Wd_w[n * 384 + 128 + k]
                                      : Wd_w[n * 384 + 256 + (k - 128)];
  else                  v = Wd_w[n * 384 + k];
  f16[e] = f2b(v);
}

// ---- prep2: i8 quantized gates weights, one wave per column ----
__global__ void prep_q(const float* __restrict__ enc_Wih,
                       const float* __restrict__ enc_Whh,
                       const float* __restrict__ dec_Whh,
                       char* __restrict__ ws8) {
  int gw = (blockIdx.x * 256 + threadIdx.x) >> 6;
  int lane = threadIdx.x & 63;
  if (gw < 512) {                        // encoder col, K=256
    int n = gw;
    float v[4]; float m = 0.f;
#pragma unroll
    for (int q = 0; q < 4; ++q) {
      int k = lane * 4 + q;
      v[q] = (k < 128) ? enc_Wih[n * 128 + k] : enc_Whh[n * 128 + (k - 128)];
      m = fmaxf(m, fabsf(v[q]));
    }
    m = wmax64(m);
    if (lane == 0) ((float*)(ws8 + SENC_B))[n] = m * C127;
    float inv = m > 0.f ? 127.f / m : 0.f;
    char* dst = ws8 + WENC8_B;
#pragma unroll
    for (int q = 0; q < 4; ++q) {
      int k = lane * 4 + q;
      int kt = k >> 6, grp = (k >> 4) & 3, b = k & 15, l16 = (n & 15) | (grp << 4);
      dst[((kt * 32 + (n >> 4)) * 64 + l16) * 16 + b] = (char)(int)rintf(v[q] * inv);
    }
  } else if (gw < 1024) {                // decoder col, K=128
    int n = gw - 512;
    float v[2]; float m = 0.f;
#pragma unroll
    for (int q = 0; q < 2; ++q) {
      int k = lane * 2 + q;
      v[q] = dec_Whh[n * 128 + k];
      m = fmaxf(m, fabsf(v[q]));
    }
    m = wmax64(m);
    if (lane == 0) ((float*)(ws8 + SDEC_B))[n] = m * C127;
    float inv = m > 0.f ? 127.f / m : 0.f;
    char* dst = ws8 + WDEC8_B;
#pragma unroll
    for (int q = 0; q < 2; ++q) {
      int k = lane * 2 + q;
      int kt = k >> 6, grp = (k >> 4) & 3, b = k & 15, l16 = (n & 15) | (grp << 4);
      dst[((kt * 32 + (n >> 4)) * 64 + l16) * 16 + b] = (char)(int)rintf(v[q] * inv);
    }
  }
}

__global__ __launch_bounds__(512, 2)
void da_rnn(const float* __restrict__ X, const float* __restrict__ y_hist,
            const float* __restrict__ We_w, const float* __restrict__ We_b,
            const float* __restrict__ ve_w,
            const float* __restrict__ enc_bih, const float* __restrict__ enc_bhh,
            const float* __restrict__ dec_Wih,
            const float* __restrict__ dec_bih, const float* __restrict__ dec_bhh,
            const float* __restrict__ Wd_b, const float* __restrict__ vd_w,
            const float* __restrict__ fc_w, const float* __restrict__ fc_b,
            const char* __restrict__ ws8, float* __restrict__ out) {
  const short* f16  = (const short*)ws8;
  const i32x4* enc8 = (const i32x4*)(ws8 + WENC8_B);
  const i32x4* dec8 = (const i32x4*)(ws8 + WDEC8_B);
  const float* senc = (const float*)(ws8 + SENC_B);
  const float* sdec = (const float*)(ws8 + SDEC_B);

  // strides: s_A8 272B=68w (68%32=4 -> 2-way, free); s_Ahc 264sh=132w (4 mod 32)
  __shared__ __align__(16) char  s_A8[16][272];   // gates A i8
  __shared__ __align__(16) short s_Ahc[16][264];  // base/dc/proj A bf16 [h;c]
  __shared__ short s_projT[4][64][65];            // enc_proj^T
  __shared__ short s_encht[4][128][66];           // enc_hiddens [r][j][t] bf16
  __shared__ float s_gates[4][512];
  __shared__ float s_base[4][64];                 // enc: base ; dec: dc
  __shared__ float s_beta[4][64];
  __shared__ float s_xr[4];
  __shared__ float2 s_wv[64];                     // (w_feat[k], ve_w[k])
  __shared__ float s_web[64], s_vd[64], s_wdb[64];
  __shared__ float s_se[512], s_sd[512];
  __shared__ float s_encb[512], s_decb[512], s_dwih[512];
  __shared__ float s_fcw[320];

  const int tid  = threadIdx.x;
  const int lane = tid & 63;
  const int w    = tid >> 6;        // wave 0..7 ; waves 0-3 own row w
  const int b0   = blockIdx.x * BB;

  // ---- init ----
  if (tid < 64) {
    s_wv[tid]  = make_float2(We_w[tid * 257 + 256], ve_w[tid]);
    s_web[tid] = We_b[tid];
    s_vd[tid]  = vd_w[tid];
    s_wdb[tid] = Wd_b[tid];
  }
  if (tid < 320) s_fcw[tid] = fc_w[tid];
  s_se[tid]   = senc[tid];
  s_sd[tid]   = sdec[tid];
  s_encb[tid] = enc_bih[tid] + enc_bhh[tid];
  s_decb[tid] = dec_bih[tid] + dec_bhh[tid];
  s_dwih[tid] = dec_Wih[tid];
  for (int i = tid; i < (16 * 272) / 4; i += 512) ((int*)s_A8)[i] = 0;
  for (int i = tid; i < (16 * 264) / 2; i += 512) ((int*)s_Ahc)[i] = 0;
  if (tid < 256) s_base[tid >> 6][tid & 63] = We_b[tid & 63];  // base_0

  // ---- register-resident weights (loaded once, L2) ----
  i32x4 wg[4][4];                       // enc gates i8, nt = w + 8i
#pragma unroll
  for (int kt = 0; kt < 4; ++kt)
#pragma unroll
    for (int i = 0; i < 4; ++i)
      wg[kt][i] = enc8[(kt * 32 + (w + 8 * i)) * 64 + lane];
  bf16x8 wb[8], wp[4];
  if (w < 4) {
#pragma unroll
    for (int kt = 0; kt < 8; ++kt)
      wb[kt] = *(const bf16x8*)(f16 + WHS_E + ((kt * 4 + w) * 64 + lane) * 8);
  } else {
#pragma unroll
    for (int kt = 0; kt < 4; ++kt)
      wp[kt] = *(const bf16x8*)(f16 + WDENC_E + ((kt * 4 + (w - 4)) * 64 + lane) * 8);
  }

  // per-row state (waves 0-3): features j0=lane, j1=lane+64
  float h0 = 0.f, c0 = 0.f, h1 = 0.f, c1 = 0.f;
  float x0 = 0.f, x1 = 0.f, xi = 0.f;
  const float* Xr = X + (size_t)(b0 + (w & 3)) * T_ * D_;
  if (w < 4) {
    x0 = Xr[lane]; x1 = Xr[64 + lane];
    xi = 6.f * cosf((2 * (lane >> 3) + 1) * 0.19634954084936207f);  // node
  }
  __syncthreads();

  // ====================== encoder ======================
  for (int t = 0; t < T_; ++t) {
    // ---- P_A: input attention, in-wave, waves 0-3 (row = w) ----
    if (w < 4) {
      float x0n = 0.f, x1n = 0.f;
      if (t < T_ - 1) { x0n = Xr[(t + 1) * D_ + lane]; x1n = Xr[(t + 1) * D_ + 64 + lane]; }
      // node eval: lane = (ni = lane>>3, kc = lane&7); 8 k-terms each
      const int kc = lane & 7;
      float p = 0.f;
      const float4* wvp = (const float4*)&s_wv[kc * 8];
      const float4* bp  = (const float4*)&s_base[w][kc * 8];
      float4 bA = bp[0], bB = bp[1];
#pragma unroll
      for (int q = 0; q < 4; ++q) {
        float4 wv = wvp[q];                       // (w_k, ve_k, w_{k+1}, ve_{k+1})
        float bb0 = (q < 2) ? ((q & 1) ? bA.z : bA.x) : ((q & 1) ? bB.z : bB.x);
        float bb1 = (q < 2) ? ((q & 1) ? bA.w : bA.y) : ((q & 1) ? bB.w : bB.y);
        p += wv.y * tanh_acc(fmaf(xi, wv.x, bb0));
        p += wv.w * tanh_acc(fmaf(xi, wv.z, bb1));
      }
      p += __shfl_xor(p, 1, 64); p += __shfl_xor(p, 2, 64); p += __shfl_xor(p, 4, 64);
      float f0 = __shfl(p,  0, 64), f1 = __shfl(p,  8, 64);
      float f2 = __shfl(p, 16, 64), f3 = __shfl(p, 24, 64);
      float f4 = __shfl(p, 32, 64), f5 = __shfl(p, 40, 64);
      float f6 = __shfl(p, 48, 64), f7 = __shfl(p, 56, 64);
      // barycentric interpolation at u = clamp(x, +-6), Cheb-1 nodes
      float sc0, sc1;
      {
        const float xb[8] = { 5.884711682f, 4.988817674f, 3.333421398f, 1.170541932f,
                             -1.170541932f, -3.333421398f, -4.988817674f, -5.884711682f};
        const float wbar[8] = { 0.1950903220f, -0.5555702330f, 0.8314696123f, -0.9807852804f,
                                0.9807852804f, -0.8314696123f, 0.5555702330f, -0.1950903220f};
        float u0 = fminf(fmaxf(x0, -6.f), 6.f), u1 = fminf(fmaxf(x1, -6.f), 6.f);
        float n0 = 0.f, d0 = 0.f, n1 = 0.f, d1 = 0.f;
        float fv[8] = {f0, f1, f2, f3, f4, f5, f6, f7};
#pragma unroll
        for (int i = 0; i < 8; ++i) {
          float dd0 = u0 - xb[i]; dd0 = copysignf(fmaxf(fabsf(dd0), 1e-5f), dd0);
          float dd1 = u1 - xb[i]; dd1 = copysignf(fmaxf(fabsf(dd1), 1e-5f), dd1);
          float t0 = wbar[i] * frcp(dd0), t1 = wbar[i] * frcp(dd1);
          n0 = fmaf(t0, fv[i], n0); d0 += t0;
          n1 = fmaf(t1, fv[i], n1); d1 += t1;
        }
        sc0 = n0 * frcp(d0); sc1 = n1 * frcp(d1);
      }
      float e0 = fexp2(sc0 * LOG2E), e1 = fexp2(sc1 * LOG2E);  // |sc|<=sum|ve|~2.6
      float sum = wsum64(e0 + e1);
      float mx  = wmax64(fmaxf(e0 * fabsf(x0), e1 * fabsf(x1)));
      float inv = mx > 0.f ? 127.f * frcp(mx) : 0.f;
      s_A8[w][lane]      = (char)(int)rintf(x0 * e0 * inv);
      s_A8[w][64 + lane] = (char)(int)rintf(x1 * e1 * inv);
      if (lane == 0) s_xr[w] = mx * frcp(127.f * sum);
      x0 = x0n; x1 = x1n;
    }
    __syncthreads();                                            // B1
    // ---- P_G: gates i8 GEMM, all 8 waves, weights in registers ----
    {
      i32x4 a0 = *(const i32x4*)&s_A8[lane & 15][  0 + ((lane >> 4) << 4)];
      i32x4 a1 = *(const i32x4*)&s_A8[lane & 15][ 64 + ((lane >> 4) << 4)];
      i32x4 a2 = *(const i32x4*)&s_A8[lane & 15][128 + ((lane >> 4) << 4)];
      i32x4 a3 = *(const i32x4*)&s_A8[lane & 15][192 + ((lane >> 4) << 4)];
      i32x4 ax[4], ah[4];
#pragma unroll
      for (int i = 0; i < 4; ++i) {
        i32x4 z = {0, 0, 0, 0};
        ax[i] = MFMAI8(a1, wg[1][i], MFMAI8(a0, wg[0][i], z));
        ah[i] = MFMAI8(a3, wg[3][i], MFMAI8(a2, wg[2][i], z));
      }
      if (lane < 16) {
        float sx0 = s_xr[0], sx1 = s_xr[1], sx2 = s_xr[2], sx3 = s_xr[3];
#pragma unroll
        for (int i = 0; i < 4; ++i) {
          int col = (w + 8 * i) * 16 + lane;
          float se = s_se[col];
          s_gates[0][col] = se * fmaf(sx0, (float)ax[i][0], C127 * (float)ah[i][0]);
          s_gates[1][col] = se * fmaf(sx1, (float)ax[i][1], C127 * (float)ah[i][1]);
          s_gates[2][col] = se * fmaf(sx2, (float)ax[i][2], C127 * (float)ah[i][2]);
          s_gates[3][col] = se * fmaf(sx3, (float)ax[i][3], C127 * (float)ah[i][3]);
        }
      }
    }
    __syncthreads();                                            // B2
    // ---- P_E: LSTM epilogue, in-wave, waves 0-3 (2 features/lane) ----
    if (w < 4) {
      float gi0 = s_gates[w][lane]       + s_encb[lane];
      float gf0 = s_gates[w][lane + 128] + s_encb[lane + 128];
      float gg0 = s_gates[w][lane + 256] + s_encb[lane + 256];
      float go0 = s_gates[w][lane + 384] + s_encb[lane + 384];
      float gi1 = s_gates[w][lane + 64]  + s_encb[lane + 64];
      float gf1 = s_gates[w][lane + 192] + s_encb[lane + 192];
      float gg1 = s_gates[w][lane + 320] + s_encb[lane + 320];
      float go1 = s_gates[w][lane + 448] + s_encb[lane + 448];
      c0 = sigm(gf0) * c0 + sigm(gi0) * tanh_acc(gg0);
      h0 = sigm(go0) * tanh_acc(c0);
      c1 = sigm(gf1) * c1 + sigm(gi1) * tanh_acc(gg1);
      h1 = sigm(go1) * tanh_acc(c1);
      s_Ahc[w][lane]        = f2b(h0);
      s_Ahc[w][lane + 64]   = f2b(h1);
      s_Ahc[w][lane + 128]  = f2b(c0);
      s_Ahc[w][lane + 192]  = f2b(c1);
      s_A8[w][128 + lane]      = (char)(int)rintf(h0 * 127.f);
      s_A8[w][128 + lane + 64] = (char)(int)rintf(h1 * 127.f);
      s_encht[w][lane][t]      = f2b(h0);
      s_encht[w][lane + 64][t] = f2b(h1);
    }
    __syncthreads();                                            // B3
    // ---- P_B: base_{t+1} (waves 0-3) | proj_t (waves 4-7), B in regs ----
    if (w < 4) {
      f32x4 acc = {0.f, 0.f, 0.f, 0.f};
#pragma unroll
      for (int kt = 0; kt < 8; ++kt) {
        bf16x8 a = *(const bf16x8*)&s_Ahc[lane & 15][kt * 32 + ((lane >> 4) << 3)];
        acc = MFMA16(a, wb[kt], acc);
      }
      if (lane < 16) {
        int col = w * 16 + lane; float bias = s_web[col];
#pragma unroll
        for (int r = 0; r < 4; ++r) s_base[r][col] = acc[r] + bias;
      }
    } else {
      f32x4 acc = {0.f, 0.f, 0.f, 0.f};
#pragma unroll
      for (int kt = 0; kt < 4; ++kt) {
        bf16x8 a = *(const bf16x8*)&s_Ahc[lane & 15][kt * 32 + ((lane >> 4) << 3)];
        acc = MFMA16(a, wp[kt], acc);
      }
      if (lane < 16) {
        int katt = (w - 4) * 16 + lane;
#pragma unroll
        for (int r = 0; r < 4; ++r) s_projT[r][katt][t] = f2b(acc[r]);
      }
    }
    __syncthreads();                                            // B4
  }

  // ====================== decoder ======================
  {
    int r = tid >> 7, j = tid & 127;
    s_Ahc[r][j] = 0; s_Ahc[r][128 + j] = 0; s_A8[r][j] = 0;
  }
  i32x4 wdg[2][8];                      // dec gates i8 (waves 4-7), nt=(w-4)*8+i
  bf16x8 wdc[8];                        // dc bf16 (waves 0-3)
  float yp = 0.f, yhd = 0.f;
  if (w >= 4) {
#pragma unroll
    for (int kt = 0; kt < 2; ++kt)
#pragma unroll
      for (int i = 0; i < 8; ++i)
        wdg[kt][i] = dec8[(kt * 32 + ((w - 4) * 8 + i)) * 64 + lane];
  } else {
#pragma unroll
    for (int kt = 0; kt < 8; ++kt)
      wdc[kt] = *(const bf16x8*)(f16 + WDDC_E + ((kt * 4 + w) * 64 + lane) * 8);
    yp = y_hist[(b0 + w) * T_ + (T_ - 1)];
    float pp = s_fcw[256 + lane] * y_hist[(b0 + w) * T_ + lane];
    yhd = wsum64(pp) + fc_b[0];
  }
  float dd0 = 0.f, dc0 = 0.f, dd1 = 0.f, dc1 = 0.f;   // d, cc (2 feats/lane)
  __syncthreads();

  for (int hs = 0; hs < HOR_; ++hs) {
    // ---- P_dG: dec gates i8 (waves 4-7) | dc bf16 (waves 0-3) ----
    if (w >= 4) {
      i32x4 a0 = *(const i32x4*)&s_A8[lane & 15][ 0 + ((lane >> 4) << 4)];
      i32x4 a1 = *(const i32x4*)&s_A8[lane & 15][64 + ((lane >> 4) << 4)];
#pragma unroll
      for (int i = 0; i < 8; ++i) {
        i32x4 z = {0, 0, 0, 0};
        i32x4 ac = MFMAI8(a1, wdg[1][i], MFMAI8(a0, wdg[0][i], z));
        if (lane < 16) {
          int col = ((w - 4) * 8 + i) * 16 + lane;
          float sd = s_sd[col] * C127;
#pragma unroll
          for (int r = 0; r < 4; ++r) s_gates[r][col] = sd * (float)ac[r];
        }
      }
    } else {
      f32x4 acc = {0.f, 0.f, 0.f, 0.f};
#pragma unroll
      for (int kt = 0; kt < 8; ++kt) {
        bf16x8 a = *(const bf16x8*)&s_Ahc[lane & 15][kt * 32 + ((lane >> 4) << 3)];
        acc = MFMA16(a, wdc[kt], acc);
      }
      if (lane < 16) {
        int col = w * 16 + lane; float bias = s_wdb[col];
#pragma unroll
        for (int r = 0; r < 4; ++r) s_base[r][col] = acc[r] + bias;
      }
    }
    __syncthreads();                                            // B1
    // ---- P_dA: attention + context + epilogue + fc, in-wave (waves 0-3) ----
    if (w < 4) {
      // scores: lane = t'
      float s = 0.f;
#pragma unroll 8
      for (int k = 0; k < 64; ++k)
        s += s_vd[k] * tanh_acc(b2f(s_projT[w][k][lane]) + s_base[w][k]);
      float e = fexp2(s * LOG2E);
      float ssum = wsum64(e);
      s_beta[w][lane] = e * frcp(ssum);
      // context: per lane features j0=lane, j1=lane+64 (same-wave LDS RAW ok)
      float cx0 = 0.f, cx1 = 0.f;
      const short* e0p = &s_encht[w][lane][0];
      const short* e1p = &s_encht[w][lane + 64][0];
#pragma unroll 8
      for (int tp = 0; tp < 64; ++tp) {
        float bta = s_beta[w][tp];
        cx0 = fmaf(bta, b2f(e0p[tp]), cx0);
        cx1 = fmaf(bta, b2f(e1p[tp]), cx1);
      }
      // LSTM epilogue (gates use OLD d via GEMM; +y_prev*dec_Wih)
      float gi0 = s_gates[w][lane]       + s_decb[lane]       + yp * s_dwih[lane];
      float gf0 = s_gates[w][lane + 128] + s_decb[lane + 128] + yp * s_dwih[lane + 128];
      float gg0 = s_gates[w][lane + 256] + s_decb[lane + 256] + yp * s_dwih[lane + 256];
      float go0 = s_gates[w][lane + 384] + s_decb[lane + 384] + yp * s_dwih[lane + 384];
      float gi1 = s_gates[w][lane + 64]  + s_decb[lane + 64]  + yp * s_dwih[lane + 64];
      float gf1 = s_gates[w][lane + 192] + s_decb[lane + 192] + yp * s_dwih[lane + 192];
      float gg1 = s_gates[w][lane + 320] + s_decb[lane + 320] + yp * s_dwih[lane + 320];
      float go1 = s_gates[w][lane + 448] + s_decb[lane + 448] + yp * s_dwih[lane + 448];
      dc0 = sigm(gf0) * dc0 + sigm(gi0) * tanh_acc(gg0);
      dd0 = sigm(go0) * tanh_acc(dc0);
      dc1 = sigm(gf1) * dc1 + sigm(gi1) * tanh_acc(gg1);
      dd1 = sigm(go1) * tanh_acc(dc1);
      // fc
      float pf = s_fcw[lane] * dd0 + s_fcw[64 + lane] * dd1
               + s_fcw[128 + lane] * cx0 + s_fcw[192 + lane] * cx1;
      pf = wsum64(pf);
      float o = pf + yhd;
      if (lane == 0) out[(b0 + w) * HOR_ + hs] = o;
      yp = o;
      // state for next P_dG
      s_Ahc[w][lane]       = f2b(dd0);
      s_Ahc[w][lane + 64]  = f2b(dd1);
      s_Ahc[w][lane + 128] = f2b(dc0);
      s_Ahc[w][lane + 192] = f2b(dc1);
      s_A8[w][lane]      = (char)(int)rintf(dd0 * 127.f);
      s_A8[w][lane + 64] = (char)(int)rintf(dd1 * 127.f);
    }
    __syncthreads();                                            // B2
  }
}

extern "C" void kernel_launch(void* const* d_in, const int* in_sizes, int n_in,
                              void* d_out, int out_size, void* d_ws, size_t ws_size,
                              hipStream_t stream) {
  (void)in_sizes; (void)n_in; (void)out_size; (void)ws_size;
  const float* X       = (const float*)d_in[0];
  const float* y_hist  = (const float*)d_in[1];
  const float* We_w    = (const float*)d_in[2];
  const float* We_b    = (const float*)d_in[3];
  const float* ve_w    = (const float*)d_in[4];
  // d_in[5] = ve_b : softmax-invariant, unused
  const float* enc_Wih = (const float*)d_in[6];
  const float* enc_Whh = (const float*)d_in[7];
  const float* enc_bih = (const float*)d_in[8];
  const float* enc_bhh = (const float*)d_in[9];
  const float* dec_Wih = (const float*)d_in[10];
  const float* dec_Whh = (const float*)d_in[11];
  const float* dec_bih = (const float*)d_in[12];
  const float* dec_bhh = (const float*)d_in[13];
  const float* Wd_w    = (const float*)d_in[14];
  const float* Wd_b    = (const float*)d_in[15];
  const float* vd_w    = (const float*)d_in[16];
  // d_in[17] = vd_b : softmax-invariant, unused
  const float* fc_w    = (const float*)d_in[18];
  const float* fc_b    = (const float*)d_in[19];

  char* ws8  = (char*)d_ws;
  float* out = (float*)d_out;

  prep_bf<<<160, 256, 0, stream>>>(We_w, Wd_w, ws8);
  prep_q <<<256, 256, 0, stream>>>(enc_Wih, enc_Whh, dec_Whh, ws8);
  da_rnn <<<B_ / BB, 512, 0, stream>>>(X, y_hist, We_w, We_b, ve_w,
                                       enc_bih, enc_bhh, dec_Wih, dec_bih, dec_bhh,
                                       Wd_b, vd_w, fc_w, fc_b, ws8, out);
}